// Round 1
// baseline (355.479 us; speedup 1.0000x reference)
//
#include <hip/hip_runtime.h>

#define BATCH 2048
#define NFEAT 256
#define DTOK  512
#define EPS   1e-5f

// One wave (64 lanes) per (batch, feature) row of D_TOKEN=512.
// Lane handles 8 contiguous d-elements: 2x float4 loads, in-register token,
// wave shuffle reduce for mean/var, 2x float4 store. Write-BW bound.
__global__ __launch_bounds__(256) void FeatureTokenizer_kernel(
    const float* __restrict__ values,
    const float* __restrict__ masks,
    const float* __restrict__ W,       // (F, 2, D)
    const float* __restrict__ bias,    // (F, D)
    const float* __restrict__ gamma,   // (D,)
    const float* __restrict__ beta,    // (D,)
    float* __restrict__ out)           // (B, F, D)
{
    const int lane = threadIdx.x & 63;
    const int wv   = threadIdx.x >> 6;
    const long long row = (long long)blockIdx.x * 4 + wv;   // [0, B*F)
    const int f  = (int)(row & (NFEAT - 1));
    const int bi = (int)(row >> 8);

    const float v = values[bi * NFEAT + f];
    const float m = masks[bi * NFEAT + f];

    const int d0 = lane * 8;

    const float4* w0p = (const float4*)(W + ((size_t)f * 2 + 0) * DTOK + d0);
    const float4* w1p = (const float4*)(W + ((size_t)f * 2 + 1) * DTOK + d0);
    const float4* bp  = (const float4*)(bias + (size_t)f * DTOK + d0);

    float4 w0v[2], w1v[2], bv[2];
    w0v[0] = w0p[0]; w0v[1] = w0p[1];
    w1v[0] = w1p[0]; w1v[1] = w1p[1];
    bv[0]  = bp[0];  bv[1]  = bp[1];

    const float* w0 = (const float*)w0v;
    const float* w1 = (const float*)w1v;
    const float* bf = (const float*)bv;

    float t[8];
    float s = 0.0f, ss = 0.0f;
#pragma unroll
    for (int j = 0; j < 8; ++j) {
        t[j] = fmaf(v, w0[j], fmaf(m, w1[j], bf[j]));
        s  += t[j];
        ss += t[j] * t[j];
    }

    // wave-wide reduction across 64 lanes
#pragma unroll
    for (int off = 1; off < 64; off <<= 1) {
        s  += __shfl_xor(s,  off, 64);
        ss += __shfl_xor(ss, off, 64);
    }

    const float mu   = s * (1.0f / DTOK);
    const float var  = ss * (1.0f / DTOK) - mu * mu;
    const float rstd = rsqrtf(var + EPS);

    const float4* gp = (const float4*)(gamma + d0);
    const float4* ep = (const float4*)(beta + d0);
    float4 gv[2], bev[2];
    gv[0] = gp[0]; gv[1] = gp[1];
    bev[0] = ep[0]; bev[1] = ep[1];
    const float* ga = (const float*)gv;
    const float* be = (const float*)bev;

    float4 o[2];
    float* op = (float*)o;
#pragma unroll
    for (int j = 0; j < 8; ++j) {
        op[j] = fmaf((t[j] - mu) * rstd, ga[j], be[j]);
    }

    float4* outp = (float4*)(out + (size_t)row * DTOK + d0);
    outp[0] = o[0];
    outp[1] = o[1];
}

extern "C" void kernel_launch(void* const* d_in, const int* in_sizes, int n_in,
                              void* d_out, int out_size, void* d_ws, size_t ws_size,
                              hipStream_t stream) {
    const float* values = (const float*)d_in[0];
    const float* masks  = (const float*)d_in[1];
    const float* W      = (const float*)d_in[2];
    const float* bias   = (const float*)d_in[3];
    const float* gamma  = (const float*)d_in[4];
    const float* beta   = (const float*)d_in[5];
    float* out = (float*)d_out;

    const long long rows = (long long)BATCH * NFEAT;   // 524288
    const int blocks = (int)(rows / 4);                // 4 waves per 256-thread block

    FeatureTokenizer_kernel<<<blocks, 256, 0, stream>>>(
        values, masks, W, bias, gamma, beta, out);
}

// Round 3
// 243.843 us; speedup vs baseline: 1.4578x; 1.4578x over previous
//
#include <hip/hip_runtime.h>

#define BATCH 2048
#define NFEAT 256
#define DTOK  512
#define EPS   1e-5f

typedef float fx4 __attribute__((ext_vector_type(4)));

// One wave (64 lanes) per (batch, feature) row of D_TOKEN=512.
// Lane handles d = lane*4 (first 1KB) and d = lane*4+256 (second 1KB) so every
// float4 load/store instruction is a fully contiguous 1KB wave-wide access.
// Wave shuffle reduce for mean/var; nontemporal stores (keep W/bias in L2).
__global__ __launch_bounds__(256) void FeatureTokenizer_kernel(
    const float* __restrict__ values,
    const float* __restrict__ masks,
    const float* __restrict__ W,       // (F, 2, D)
    const float* __restrict__ bias,    // (F, D)
    const float* __restrict__ gamma,   // (D,)
    const float* __restrict__ beta,    // (D,)
    float* __restrict__ out)           // (B, F, D)
{
    const int lane = threadIdx.x & 63;
    const int wv   = threadIdx.x >> 6;
    const long long row = (long long)blockIdx.x * 4 + wv;   // [0, B*F)
    const int f  = (int)(row & (NFEAT - 1));
    const int bi = (int)(row >> 8);

    const float v = values[bi * NFEAT + f];
    const float m = masks[bi * NFEAT + f];

    const int dA = lane * 4;        // element index in first 1KB half
    const int dB = dA + 256;        // second 1KB half

    const float* w0base = W + ((size_t)f * 2 + 0) * DTOK;
    const float* w1base = W + ((size_t)f * 2 + 1) * DTOK;
    const float* bbase  = bias + (size_t)f * DTOK;

    fx4 w0a = *(const fx4*)(w0base + dA);
    fx4 w0b = *(const fx4*)(w0base + dB);
    fx4 w1a = *(const fx4*)(w1base + dA);
    fx4 w1b = *(const fx4*)(w1base + dB);
    fx4 ba  = *(const fx4*)(bbase  + dA);
    fx4 bb  = *(const fx4*)(bbase  + dB);

    float t[8];
#pragma unroll
    for (int j = 0; j < 4; ++j) {
        t[j]     = fmaf(v, w0a[j], fmaf(m, w1a[j], ba[j]));
        t[j + 4] = fmaf(v, w0b[j], fmaf(m, w1b[j], bb[j]));
    }

    float s = 0.0f, ss = 0.0f;
#pragma unroll
    for (int j = 0; j < 8; ++j) {
        s  += t[j];
        ss += t[j] * t[j];
    }

    // wave-wide butterfly reduction across 64 lanes
#pragma unroll
    for (int off = 1; off < 64; off <<= 1) {
        s  += __shfl_xor(s,  off, 64);
        ss += __shfl_xor(ss, off, 64);
    }

    const float mu   = s * (1.0f / DTOK);
    const float var  = ss * (1.0f / DTOK) - mu * mu;
    const float rstd = rsqrtf(var + EPS);

    fx4 ga = *(const fx4*)(gamma + dA);
    fx4 gb = *(const fx4*)(gamma + dB);
    fx4 ea = *(const fx4*)(beta  + dA);
    fx4 eb = *(const fx4*)(beta  + dB);

    fx4 oA, oB;
#pragma unroll
    for (int j = 0; j < 4; ++j) {
        oA[j] = fmaf((t[j]     - mu) * rstd, ga[j], ea[j]);
        oB[j] = fmaf((t[j + 4] - mu) * rstd, gb[j], eb[j]);
    }

    float* orow = out + (size_t)row * DTOK;
    __builtin_nontemporal_store(oA, (fx4*)(orow + dA));
    __builtin_nontemporal_store(oB, (fx4*)(orow + dB));
}

extern "C" void kernel_launch(void* const* d_in, const int* in_sizes, int n_in,
                              void* d_out, int out_size, void* d_ws, size_t ws_size,
                              hipStream_t stream) {
    const float* values = (const float*)d_in[0];
    const float* masks  = (const float*)d_in[1];
    const float* W      = (const float*)d_in[2];
    const float* bias   = (const float*)d_in[3];
    const float* gamma  = (const float*)d_in[4];
    const float* beta   = (const float*)d_in[5];
    float* out = (float*)d_out;

    const long long rows = (long long)BATCH * NFEAT;   // 524288
    const int blocks = (int)(rows / 4);                // 4 waves per 256-thread block

    FeatureTokenizer_kernel<<<blocks, 256, 0, stream>>>(
        values, masks, W, bias, gamma, beta, out);
}

// Round 4
// 208.959 us; speedup vs baseline: 1.7012x; 1.1669x over previous
//
#include <hip/hip_runtime.h>

#define BATCH  2048
#define NFEAT  256
#define DTOK   512
#define EPS    1e-5f
#define BCHUNK 16   // batches per wave

typedef float fx4 __attribute__((ext_vector_type(4)));

// One wave (64 lanes) per feature f, looping over BCHUNK batches.
// W0/W1/bias/gamma/beta fragments stay in registers across the loop, so the
// per-row L2 read traffic is just the scalar (v, m) pair (cooperatively
// loaded by lanes 0..15, broadcast via shfl). Lane owns d = lane*4 and
// d = lane*4+256 -> every float4 access is a contiguous 1KB wave-wide op.
// Nontemporal stores keep the 1GB output stream from thrashing L2.
__global__ __launch_bounds__(256) void FeatureTokenizer_kernel(
    const float* __restrict__ values,
    const float* __restrict__ masks,
    const float* __restrict__ W,       // (F, 2, D)
    const float* __restrict__ bias,    // (F, D)
    const float* __restrict__ gamma,   // (D,)
    const float* __restrict__ beta,    // (D,)
    float* __restrict__ out)           // (B, F, D)
{
    const int lane = threadIdx.x & 63;
    const int wv   = threadIdx.x >> 6;
    const int bid  = blockIdx.x;        // 8192 blocks
    const int fg   = bid & 63;          // feature group (4 features each)
    const int bc   = bid >> 6;          // batch chunk (16 batches each)
    const int f    = fg * 4 + wv;
    const int b0   = bc * BCHUNK;

    const int dA = lane * 4;            // first 1KB half
    const int dB = dA + 256;            // second 1KB half

    const float* w0base = W + ((size_t)f * 2 + 0) * DTOK;
    const float* w1base = W + ((size_t)f * 2 + 1) * DTOK;
    const float* bbase  = bias + (size_t)f * DTOK;

    const fx4 w0a = *(const fx4*)(w0base + dA);
    const fx4 w0b = *(const fx4*)(w0base + dB);
    const fx4 w1a = *(const fx4*)(w1base + dA);
    const fx4 w1b = *(const fx4*)(w1base + dB);
    const fx4 ba  = *(const fx4*)(bbase  + dA);
    const fx4 bb  = *(const fx4*)(bbase  + dB);
    const fx4 ga  = *(const fx4*)(gamma + dA);
    const fx4 gb  = *(const fx4*)(gamma + dB);
    const fx4 ea  = *(const fx4*)(beta  + dA);
    const fx4 eb  = *(const fx4*)(beta  + dB);

    // cooperative preload of the BCHUNK (v, m) pairs: lane i holds batch b0+i
    float vv = 0.0f, mm = 0.0f;
    if (lane < BCHUNK) {
        vv = values[(size_t)(b0 + lane) * NFEAT + f];
        mm = masks [(size_t)(b0 + lane) * NFEAT + f];
    }

    for (int i = 0; i < BCHUNK; ++i) {
        const float v = __shfl(vv, i, 64);
        const float m = __shfl(mm, i, 64);

        float t[8];
#pragma unroll
        for (int j = 0; j < 4; ++j) {
            t[j]     = fmaf(v, w0a[j], fmaf(m, w1a[j], ba[j]));
            t[j + 4] = fmaf(v, w0b[j], fmaf(m, w1b[j], bb[j]));
        }

        float s = 0.0f, ss = 0.0f;
#pragma unroll
        for (int j = 0; j < 8; ++j) {
            s  += t[j];
            ss += t[j] * t[j];
        }
#pragma unroll
        for (int off = 1; off < 64; off <<= 1) {
            s  += __shfl_xor(s,  off, 64);
            ss += __shfl_xor(ss, off, 64);
        }

        const float mu   = s * (1.0f / DTOK);
        const float var  = ss * (1.0f / DTOK) - mu * mu;
        const float rstd = rsqrtf(var + EPS);

        fx4 oA, oB;
#pragma unroll
        for (int j = 0; j < 4; ++j) {
            oA[j] = fmaf((t[j]     - mu) * rstd, ga[j], ea[j]);
            oB[j] = fmaf((t[j + 4] - mu) * rstd, gb[j], eb[j]);
        }

        float* orow = out + ((size_t)(b0 + i) * NFEAT + f) * DTOK;
        __builtin_nontemporal_store(oA, (fx4*)(orow + dA));
        __builtin_nontemporal_store(oB, (fx4*)(orow + dB));
    }
}

extern "C" void kernel_launch(void* const* d_in, const int* in_sizes, int n_in,
                              void* d_out, int out_size, void* d_ws, size_t ws_size,
                              hipStream_t stream) {
    const float* values = (const float*)d_in[0];
    const float* masks  = (const float*)d_in[1];
    const float* W      = (const float*)d_in[2];
    const float* bias   = (const float*)d_in[3];
    const float* gamma  = (const float*)d_in[4];
    const float* beta   = (const float*)d_in[5];
    float* out = (float*)d_out;

    // 64 feature-groups x 128 batch-chunks
    const int blocks = 64 * (BATCH / BCHUNK);
    FeatureTokenizer_kernel<<<blocks, 256, 0, stream>>>(
        values, masks, W, bias, gamma, beta, out);
}

// Round 5
// 199.321 us; speedup vs baseline: 1.7835x; 1.0484x over previous
//
#include <hip/hip_runtime.h>

#define BATCH  2048
#define NFEAT  256
#define DTOK   512
#define EPS    1e-5f
#define BCHUNK 16   // batches per wave

typedef float fx4 __attribute__((ext_vector_type(4)));

// One wave (64 lanes) per feature f, looping over BCHUNK batches.
// W0/W1/bias/gamma/beta fragments live in registers. Row statistics come from
// 9 per-feature moments (Sw0, Sw1, Sb, Sw0^2, Sw1^2, Sb^2, Sw0w1, Sw0b, Sw1b)
// reduced ONCE per wave, so the per-row loop has ZERO cross-lane ops:
//   mu  = (v*A0 + m*A1 + A2)/D
//   E2  = (v^2*B00 + m^2*B11 + B22 + 2(vm*B01 + v*B02 + m*B12))/D
//   var = E2 - mu^2
// (v,m) are wave-uniform -> scalar loads prefetched into SGPRs.
// Lane owns d = lane*4 and d = lane*4+256 -> contiguous 1KB wave-wide accesses.
__global__ __launch_bounds__(256) void FeatureTokenizer_kernel(
    const float* __restrict__ values,
    const float* __restrict__ masks,
    const float* __restrict__ W,       // (F, 2, D)
    const float* __restrict__ bias,    // (F, D)
    const float* __restrict__ gamma,   // (D,)
    const float* __restrict__ beta,    // (D,)
    float* __restrict__ out)           // (B, F, D)
{
    const int lane = threadIdx.x & 63;
    const int wv   = threadIdx.x >> 6;
    const int bid  = blockIdx.x;        // 8192 blocks
    const int fg   = bid & 63;          // feature group (4 features each)
    const int bc   = bid >> 6;          // batch chunk (16 batches each)
    const int f    = fg * 4 + wv;
    const int b0   = bc * BCHUNK;

    const int dA = lane * 4;            // first 1KB half
    const int dB = dA + 256;            // second 1KB half

    const float* w0base = W + ((size_t)f * 2 + 0) * DTOK;
    const float* w1base = W + ((size_t)f * 2 + 1) * DTOK;
    const float* bbase  = bias + (size_t)f * DTOK;

    const fx4 w0a = *(const fx4*)(w0base + dA);
    const fx4 w0b = *(const fx4*)(w0base + dB);
    const fx4 w1a = *(const fx4*)(w1base + dA);
    const fx4 w1b = *(const fx4*)(w1base + dB);
    const fx4 ba  = *(const fx4*)(bbase  + dA);
    const fx4 bb  = *(const fx4*)(bbase  + dB);
    const fx4 ga  = *(const fx4*)(gamma + dA);
    const fx4 gb  = *(const fx4*)(gamma + dB);
    const fx4 ea  = *(const fx4*)(beta  + dA);
    const fx4 eb  = *(const fx4*)(beta  + dB);

    // per-lane partial moments over this lane's 8 elements
    float a0 = 0, a1 = 0, a2 = 0;
    float b00 = 0, b11 = 0, b22 = 0, b01 = 0, b02 = 0, b12 = 0;
#pragma unroll
    for (int j = 0; j < 4; ++j) {
        const float u0 = w0a[j], u1 = w1a[j], ub = ba[j];
        const float x0 = w0b[j], x1 = w1b[j], xb = bb[j];
        a0 += u0 + x0;  a1 += u1 + x1;  a2 += ub + xb;
        b00 = fmaf(u0, u0, fmaf(x0, x0, b00));
        b11 = fmaf(u1, u1, fmaf(x1, x1, b11));
        b22 = fmaf(ub, ub, fmaf(xb, xb, b22));
        b01 = fmaf(u0, u1, fmaf(x0, x1, b01));
        b02 = fmaf(u0, ub, fmaf(x0, xb, b02));
        b12 = fmaf(u1, ub, fmaf(x1, xb, b12));
    }

    // one-time wave-wide butterfly reduce of the 9 moments
#pragma unroll
    for (int off = 1; off < 64; off <<= 1) {
        a0  += __shfl_xor(a0,  off, 64);
        a1  += __shfl_xor(a1,  off, 64);
        a2  += __shfl_xor(a2,  off, 64);
        b00 += __shfl_xor(b00, off, 64);
        b11 += __shfl_xor(b11, off, 64);
        b22 += __shfl_xor(b22, off, 64);
        b01 += __shfl_xor(b01, off, 64);
        b02 += __shfl_xor(b02, off, 64);
        b12 += __shfl_xor(b12, off, 64);
    }

    // prefetch wave-uniform (v, m) pairs into SGPRs
    float vs[BCHUNK], ms[BCHUNK];
#pragma unroll
    for (int i = 0; i < BCHUNK; ++i) {
        vs[i] = values[(size_t)(b0 + i) * NFEAT + f];
        ms[i] = masks [(size_t)(b0 + i) * NFEAT + f];
    }

#pragma unroll 4
    for (int i = 0; i < BCHUNK; ++i) {
        const float v = vs[i], m = ms[i];

        const float S  = fmaf(v, a0, fmaf(m, a1, a2));
        const float mu = S * (1.0f / DTOK);
        const float E2 = fmaf(v * v, b00, fmaf(m * m, b11,
                         fmaf(2.0f * v * m, b01,
                         fmaf(2.0f * v, b02, fmaf(2.0f * m, b12, b22)))));
        const float var  = E2 * (1.0f / DTOK) - mu * mu;
        const float rstd = rsqrtf(var + EPS);

        fx4 oA, oB;
#pragma unroll
        for (int j = 0; j < 4; ++j) {
            const float tA = fmaf(v, w0a[j], fmaf(m, w1a[j], ba[j]));
            const float tB = fmaf(v, w0b[j], fmaf(m, w1b[j], bb[j]));
            oA[j] = fmaf((tA - mu) * rstd, ga[j], ea[j]);
            oB[j] = fmaf((tB - mu) * rstd, gb[j], eb[j]);
        }

        float* orow = out + ((size_t)(b0 + i) * NFEAT + f) * DTOK;
        __builtin_nontemporal_store(oA, (fx4*)(orow + dA));
        __builtin_nontemporal_store(oB, (fx4*)(orow + dB));
    }
}

extern "C" void kernel_launch(void* const* d_in, const int* in_sizes, int n_in,
                              void* d_out, int out_size, void* d_ws, size_t ws_size,
                              hipStream_t stream) {
    const float* values = (const float*)d_in[0];
    const float* masks  = (const float*)d_in[1];
    const float* W      = (const float*)d_in[2];
    const float* bias   = (const float*)d_in[3];
    const float* gamma  = (const float*)d_in[4];
    const float* beta   = (const float*)d_in[5];
    float* out = (float*)d_out;

    // 64 feature-groups x 128 batch-chunks
    const int blocks = 64 * (BATCH / BCHUNK);
    FeatureTokenizer_kernel<<<blocks, 256, 0, stream>>>(
        values, masks, W, bias, gamma, beta, out);
}